// Round 7
// baseline (298.282 us; speedup 1.0000x reference)
//
#include <hip/hip_runtime.h>
#include <hip/hip_bf16.h>
#include <cstdint>

// Problem constants
#define TT   32768
#define DD   256
#define KV   16      // K == V == 16
#define NBLK 2
#define HH   256
#define CH   64              // scan chunk length
#define NCH  (TT / CH)       // 512 chunks

typedef __attribute__((ext_vector_type(8))) short bf16x8;   // 8 bf16 in 4 VGPRs
typedef __attribute__((ext_vector_type(4))) float f32x4;

__device__ __forceinline__ float phi_f(float x)  { return x > 0.f ? x + 1.f : expf(x); }
__device__ __forceinline__ float lrelu_f(float x){ return x > 0.f ? x : 0.01f * x; }
__device__ __forceinline__ unsigned short f2bf(float f) {   // RNE f32->bf16
  unsigned u = __float_as_uint(f);
  u += 0x7fffu + ((u >> 16) & 1u);
  return (unsigned short)(u >> 16);
}
__device__ __forceinline__ float bf2f(unsigned short h) {
  return __uint_as_float(((unsigned)h) << 16);
}

// ---------------------------------------------------------------------------
// start-dtype detection (unchanged)
// ---------------------------------------------------------------------------
__global__ void k_detect(const void* __restrict__ startp, int* __restrict__ flags) {
  int stride = gridDim.x * blockDim.x;
  for (int t = blockIdx.x * blockDim.x + threadIdx.x; t < TT / 4; t += stride) {
    unsigned u = ((const unsigned*)startp)[t];
    if (u > 1u) atomicOr(&flags[0], 1);
    float f = ((const float*)startp)[t];
    if (!(f == 0.f || f == 1.f)) atomicOr(&flags[1], 1);
  }
}

__global__ void k_canon(const void* __restrict__ startp, const int* __restrict__ flags,
                        float* __restrict__ start_f) {
  int v32 = flags[0], vf = flags[1];
  int stride = gridDim.x * blockDim.x;
  for (int t = blockIdx.x * blockDim.x + threadIdx.x; t < TT; t += stride) {
    bool s;
    if (v32 == 0)     s = ((const unsigned*)startp)[t] != 0u;
    else if (vf == 0) s = ((const float*)startp)[t] != 0.f;
    else              s = ((const unsigned char*)startp)[t] != 0;
    start_f[t] = s ? 1.f : 0.f;
  }
}

// ---------------------------------------------------------------------------
// Weight conversions (unchanged)
// ---------------------------------------------------------------------------
__global__ __launch_bounds__(256) void k_cvtbig(
    const float* __restrict__ s0, const float* __restrict__ s1, const float* __restrict__ s2,
    unsigned short* __restrict__ d0, unsigned short* __restrict__ d1,
    unsigned short* __restrict__ d2, int n) {
  int i = (blockIdx.x * 256 + threadIdx.x) * 8;
  const float* s; unsigned short* d;
  if (i < n)            { s = s0; d = d0; }
  else if (i < 2 * n)   { s = s1; d = d1; i -= n; }
  else if (i < 3 * n)   { s = s2; d = d2; i -= 2 * n; }
  else return;
  float4 a = *(const float4*)(s + i);
  float4 b = *(const float4*)(s + i + 4);
  float vals[8] = {a.x, a.y, a.z, a.w, b.x, b.y, b.z, b.w};
  bf16x8 t;
#pragma unroll
  for (int j = 0; j < 8; j++) t[j] = (short)f2bf(vals[j]);
  *(bf16x8*)(d + i) = t;
}

__global__ __launch_bounds__(256) void k_cvtproj(
    const float* __restrict__ Wk, const float* __restrict__ Wq, const float* __restrict__ Wv,
    unsigned short* __restrict__ wh, unsigned short* __restrict__ wl) {
  int t8 = blockIdx.x * 256 + threadIdx.x;
  if (t8 >= NBLK * 48 * 256 / 8) return;
  int e = t8 * 8;
  int b = e / (48 * 256);
  int rem = e - b * 48 * 256;
  int o = rem / (16 * 256);
  int nr = rem - o * 16 * 256;
  const float* src = (o == 0 ? Wk : o == 1 ? Wq : Wv) + b * 16 * 256 + nr;
  float4 a = *(const float4*)src;
  float4 c = *(const float4*)(src + 4);
  float vals[8] = {a.x, a.y, a.z, a.w, c.x, c.y, c.z, c.w};
  bf16x8 th, tl;
#pragma unroll
  for (int j = 0; j < 8; j++) {
    unsigned short h = f2bf(vals[j]);
    th[j] = (short)h;
    tl[j] = (short)f2bf(vals[j] - bf2f(h));
  }
  *(bf16x8*)(wh + e) = th;
  *(bf16x8*)(wl + e) = tl;
}

// Wm1 [NB][256][16] -> hi/lo [NB][256][32] zero-padded in k (16..31 = 0)
__global__ __launch_bounds__(256) void k_cvtm1(
    const float* __restrict__ Wm1,
    unsigned short* __restrict__ h, unsigned short* __restrict__ l) {
  int row = blockIdx.x * 256 + threadIdx.x;
  if (row >= NBLK * 256) return;
  const float* s = Wm1 + row * 16;
  bf16x8 th0, tl0, th1, tl1, z;
#pragma unroll
  for (int j = 0; j < 8; j++) {
    float v0 = s[j], v1 = s[j + 8];
    unsigned short h0 = f2bf(v0), h1 = f2bf(v1);
    th0[j] = (short)h0; tl0[j] = (short)f2bf(v0 - bf2f(h0));
    th1[j] = (short)h1; tl1[j] = (short)f2bf(v1 - bf2f(h1));
    z[j] = 0;
  }
  unsigned short* dh = h + row * 32;
  unsigned short* dl = l + row * 32;
  *(bf16x8*)(dh) = th0;  *(bf16x8*)(dh + 8) = th1;
  *(bf16x8*)(dh + 16) = z; *(bf16x8*)(dh + 24) = z;
  *(bf16x8*)(dl) = tl0;  *(bf16x8*)(dl + 8) = tl1;
  *(bf16x8*)(dl + 16) = z; *(bf16x8*)(dl + 24) = z;
}

// ---------------------------------------------------------------------------
// Fused MFMA projection + per-chunk tails (unchanged from round 6)
// ---------------------------------------------------------------------------
__global__ __launch_bounds__(256) void k_projt(
    const float* __restrict__ x,
    const unsigned short* __restrict__ wh, const unsigned short* __restrict__ wl,
    const float* __restrict__ bv, const float* __restrict__ start_f,
    float* __restrict__ kout, float* __restrict__ qout, float* __restrict__ vout,
    float* __restrict__ tails_s, float* __restrict__ tails_zs,
    float* __restrict__ tails_flag) {
  __shared__ unsigned short xh[64 * 256];   // 32 KB swizzled; later kc/vc overlay
  __shared__ unsigned short xl[64 * 256];   // 32 KB swizzled
  __shared__ float stc[CH];
  __shared__ int lsS;
  float* kc = (float*)xh;                   // [64][16] overlay after MFMA
  float* vc = kc + 64 * 16;                 // [64][16]

  int tid = threadIdx.x, wg = blockIdx.x;
  size_t rbase = (size_t)wg * 64;
  const float* xs = x + rbase * DD;
#pragma unroll
  for (int i = 0; i < 8; i++) {
    int idx = tid + i * 256;
    int row = idx >> 5, c8 = idx & 31;
    const float* p = xs + row * DD + c8 * 8;
    float4 a = *(const float4*)p;
    float4 b = *(const float4*)(p + 4);
    float vals[8] = {a.x, a.y, a.z, a.w, b.x, b.y, b.z, b.w};
    bf16x8 th, tl;
#pragma unroll
    for (int j = 0; j < 8; j++) {
      unsigned short h = f2bf(vals[j]);
      th[j] = (short)h;
      tl[j] = (short)f2bf(vals[j] - bf2f(h));
    }
    int off = row * 512 + ((c8 * 16) ^ ((row & 7) << 4));
    *(bf16x8*)((char*)xh + off) = th;
    *(bf16x8*)((char*)xl + off) = tl;
  }
  if (tid < CH) stc[tid] = start_f[wg * CH + tid];
  __syncthreads();

  int lane = tid & 63, wv = tid >> 6, lg = lane >> 4, lr = lane & 15;
  int r = wv * 16 + lr;
  f32x4 acc[3];
#pragma unroll
  for (int o = 0; o < 3; o++) acc[o] = (f32x4){0.f, 0.f, 0.f, 0.f};

#pragma unroll
  for (int kk = 0; kk < 8; kk++) {
    int kbyte = kk * 64 + lg * 16;
    int off = r * 512 + (kbyte ^ ((r & 7) << 4));
    bf16x8 ah = *(bf16x8*)((char*)xh + off);
    bf16x8 al = *(bf16x8*)((char*)xl + off);
#pragma unroll
    for (int o = 0; o < 3; o++) {
      bf16x8 bh = *(const bf16x8*)((const char*)wh + (o * 16 + lr) * 512 + kbyte);
      bf16x8 bl = *(const bf16x8*)((const char*)wl + (o * 16 + lr) * 512 + kbyte);
      acc[o] = __builtin_amdgcn_mfma_f32_16x16x32_bf16(ah, bh, acc[o], 0, 0, 0);
      acc[o] = __builtin_amdgcn_mfma_f32_16x16x32_bf16(al, bh, acc[o], 0, 0, 0);
      acc[o] = __builtin_amdgcn_mfma_f32_16x16x32_bf16(ah, bl, acc[o], 0, 0, 0);
    }
  }
  __syncthreads();   // all MFMA LDS reads done; xh may now be overlaid

  float bvv = bv[lr];
#pragma unroll
  for (int rg = 0; rg < 4; rg++) {
    int rl = wv * 16 + lg * 4 + rg;
    size_t g = rbase + rl;
    float kvl = phi_f(acc[0][rg]);
    float vvl = acc[2][rg] + bvv;
    kout[g * KV + lr] = kvl;
    qout[g * KV + lr] = phi_f(acc[1][rg]);
    vout[g * KV + lr] = vvl;
    kc[rl * KV + lr] = kvl;
    vc[rl * KV + lr] = vvl;
  }
  // last-start index via wave-0 ballot
  if (tid < 64) {
    unsigned long long mask = __ballot(stc[tid] != 0.f);
    if (tid == 0) lsS = mask ? (63 - __builtin_clzll(mask)) : -1;
  }
  __syncthreads();
  int ls = lsS;
  int t0 = ls < 0 ? 0 : ls;
  {
    int i = tid >> 4, j = tid & 15;
    float s = 0.f;
    for (int t = t0; t < CH; t++) s += kc[t * KV + i] * vc[t * KV + j];
    tails_s[(size_t)wg * 256 + tid] = s;
  }
  if (tid < 64) {
    float ks = 0.f;
    if (tid >= t0) {
#pragma unroll
      for (int i = 0; i < KV; i++) ks += kc[tid * KV + i];
    }
#pragma unroll
    for (int m = 1; m < 64; m <<= 1) ks += __shfl_xor(ks, m);
    if (tid == 0) {
      tails_zs[wg] = ks;
      tails_flag[wg] = (ls >= 0) ? 1.f : 0.f;
    }
  }
}

// ---------------------------------------------------------------------------
// Attention core (unchanged; S stride 65)
// ---------------------------------------------------------------------------
#define SP 65
__global__ __launch_bounds__(256) void k_att(
    const float* __restrict__ q, const float* __restrict__ k,
    const float* __restrict__ v, const float* __restrict__ start_f,
    const float* __restrict__ tails_s, const float* __restrict__ tails_zs,
    const float* __restrict__ tails_flag,
    const float* __restrict__ s0, const float* __restrict__ z0,
    float* __restrict__ att) {
  __shared__ float qc[CH * KV], kc[CH * KV], vc[CH * KV], stc[CH];
  __shared__ float S[CH * SP];
  __shared__ float carry[256];
  __shared__ float ksum[CH], zsl[CH], qsum[CH];
  __shared__ int ns[CH];
  __shared__ float czs_s;
  int c = blockIdx.x, tid = threadIdx.x;
  size_t base = (size_t)c * CH * KV;
  for (int u = tid; u < CH * KV; u += 256) {
    qc[u] = q[base + u]; kc[u] = k[base + u]; vc[u] = v[base + u];
  }
  if (tid < CH) stc[tid] = start_f[c * CH + tid];
  __syncthreads();
  if (tid < CH) {
    int cnt = 0;
    for (int u = 0; u <= tid; u++) cnt += (stc[u] != 0.f);
    ns[tid] = cnt;
    float ks = 0.f, qs = 0.f;
    for (int i = 0; i < KV; i++) { ks += kc[tid * KV + i]; qs += qc[tid * KV + i]; }
    ksum[tid] = ks; qsum[tid] = qs;
  }
  __syncthreads();
  if (tid < CH) {
    float acc = 0.f;
    for (int u = tid; u >= 0; u--) { acc += ksum[u]; if (stc[u] != 0.f) break; }
    zsl[tid] = acc;
  }
  {
    float accs = 0.f, aczs = 0.f;
    int cc = c - 1;
    for (;;) {
      if (cc < 0) {
        accs += s0[tid];
        if (tid == 0) { float z = 0.f; for (int i = 0; i < KV; i++) z += z0[i]; aczs += z; }
        break;
      }
      float fl = tails_flag[cc];
      accs += tails_s[(size_t)cc * 256 + tid];
      if (tid == 0) aczs += tails_zs[cc];
      if (fl != 0.f) break;
      cc--;
    }
    carry[tid] = accs;
    if (tid == 0) czs_s = aczs;
  }
  __syncthreads();
  {
    int t = tid >> 2, g = tid & 3;
    for (int u = 0; u < 16; u++) {
      int tp = g * 16 + u;
      float val = 0.f;
      if (tp <= t && ns[tp] == ns[t]) {
        float dot = 0.f;
        for (int i = 0; i < KV; i++) dot += qc[t * KV + i] * kc[tp * KV + i];
        val = dot;
      }
      S[t * SP + tp] = val;
    }
  }
  __syncthreads();
  float czs = czs_s;
  int j = tid & 15, tr = tid >> 4;
  for (int p = 0; p < 4; p++) {
    int t = p * 16 + tr;
    float numer = 0.f;
    for (int tp = 0; tp < CH; tp++) numer += S[t * SP + tp] * vc[tp * KV + j];
    float zs = zsl[t];
    if (ns[t] == 0) {
      float cn = 0.f;
      for (int i = 0; i < KV; i++) cn += qc[t * KV + i] * carry[i * KV + j];
      numer += cn;
      zs += czs;
    }
    float denom = fmaxf(zs * qsum[t], 1e-6f);
    att[base + t * KV + j] = numer / denom;
  }
}

// ---------------------------------------------------------------------------
// All-MFMA MLP + skip + LayerNorm — 32-ROW blocks (grid 1024 -> 4 blocks/CU,
// 16 waves/CU). Wave owns 32x64. x tile prefetched into LDS (bf16-hi,
// swizzled) at kernel start: stage C reads become ds_read_b128, HBM latency
// overlaps stages A/B. LDS 37KB, __launch_bounds__(256,4) -> VGPR cap 128.
// ---------------------------------------------------------------------------
#define A1S 40   // padded row stride (shorts) for att hi/lo staging
template<int WY, int WX>
__global__ __launch_bounds__(256, 4) void k_mlp6(
    const float* __restrict__ att, const float* __restrict__ xsrc,
    const unsigned short* __restrict__ wm1h, const unsigned short* __restrict__ wm1l,
    const float* __restrict__ bm1,
    const unsigned short* __restrict__ Wm2b, const float* __restrict__ bm2,
    const unsigned short* __restrict__ Wm3b, const float* __restrict__ bm3,
    const unsigned short* __restrict__ Wskb, const float* __restrict__ bsk,
    const float* __restrict__ lnw, const float* __restrict__ lnb,
    float* __restrict__ yout, float* __restrict__ xnext) {
  __shared__ unsigned short hb[32 * 256];     // 16KB swizzled bf16 (h1 then h2)
  __shared__ unsigned short xsh[32 * 256];    // 16KB swizzled bf16-hi x tile
  __shared__ __align__(16) char uni[5120];    // aoh/aol, later LN scratch
  unsigned short* aoh = (unsigned short*)uni; // [32][A1S]
  unsigned short* aol = aoh + 32 * A1S;
  float* redS = (float*)uni;                  // [128]
  float* redQ = redS + 128;
  float* mrow = redQ + 128;                   // [32]
  float* irow = mrow + 32;

  int tid = threadIdx.x, wg = blockIdx.x;
  size_t rbase = (size_t)wg * 32;

  // ---- prefetch x tile -> xsh (bf16 hi, swizzled): 4 x (2 float4) per thread
  {
    const float* xs0 = xsrc + rbase * DD;
#pragma unroll
    for (int i = 0; i < 4; i++) {
      int idx = tid + i * 256;              // 8-elem group, 0..1023
      int row = idx >> 5, c8 = idx & 31;
      const float* p = xs0 + row * DD + c8 * 8;
      float4 a = *(const float4*)p;
      float4 b = *(const float4*)(p + 4);
      bf16x8 th;
      th[0] = (short)f2bf(a.x); th[1] = (short)f2bf(a.y);
      th[2] = (short)f2bf(a.z); th[3] = (short)f2bf(a.w);
      th[4] = (short)f2bf(b.x); th[5] = (short)f2bf(b.y);
      th[6] = (short)f2bf(b.z); th[7] = (short)f2bf(b.w);
      *(bf16x8*)((char*)xsh + row * 512 + ((c8 * 16) ^ ((row & 7) << 4))) = th;
    }
  }
  // ---- att -> aoh/aol (K zero-padded 16..31)
  for (int idx = tid; idx < 32 * 32; idx += 256) {
    int row = idx >> 5, col = idx & 31;
    float v = (col < 16) ? att[(rbase + row) * KV + col] : 0.f;
    unsigned short h = f2bf(v);
    aoh[row * A1S + col] = h;
    aol[row * A1S + col] = f2bf(v - bf2f(h));
  }
  __syncthreads();

  int lane = tid & 63, wv = tid >> 6, lg = lane >> 4, lr = lane & 15;
  int nc0 = wv * 64;          // wave's 64-column slice

  f32x4 acc[2][4];
#pragma unroll
  for (int a = 0; a < 2; a++)
#pragma unroll
    for (int b = 0; b < 4; b++) acc[a][b] = (f32x4){0.f, 0.f, 0.f, 0.f};

  // ---- stage A (MFMA): h1 = lrelu(att@Wm1^T + bm1)
  {
    bf16x8 b1h[4], b1l[4];
#pragma unroll
    for (int nt = 0; nt < 4; nt++) {
      int n = nc0 + nt * 16 + lr;
      b1h[nt] = *(const bf16x8*)(wm1h + n * 32 + lg * 8);
      b1l[nt] = *(const bf16x8*)(wm1l + n * 32 + lg * 8);
    }
#pragma unroll
    for (int mt = 0; mt < 2; mt++) {
      int r = mt * 16 + lr;
      bf16x8 ah = *(bf16x8*)(aoh + r * A1S + lg * 8);
      bf16x8 al = *(bf16x8*)(aol + r * A1S + lg * 8);
#pragma unroll
      for (int nt = 0; nt < 4; nt++) {
        acc[mt][nt] = __builtin_amdgcn_mfma_f32_16x16x32_bf16(ah, b1h[nt], acc[mt][nt], 0, 0, 0);
        acc[mt][nt] = __builtin_amdgcn_mfma_f32_16x16x32_bf16(al, b1h[nt], acc[mt][nt], 0, 0, 0);
        acc[mt][nt] = __builtin_amdgcn_mfma_f32_16x16x32_bf16(ah, b1l[nt], acc[mt][nt], 0, 0, 0);
      }
    }
  }
  {
    float bm1v[4];
#pragma unroll
    for (int nt = 0; nt < 4; nt++) bm1v[nt] = bm1[nc0 + nt * 16 + lr];
#pragma unroll
    for (int mt = 0; mt < 2; mt++)
#pragma unroll
      for (int nt = 0; nt < 4; nt++)
#pragma unroll
        for (int rg = 0; rg < 4; rg++) {
          int r = mt * 16 + lg * 4 + rg;
          int cc = nc0 + nt * 16 + lr;
          *(unsigned short*)((char*)hb + r * 512 + ((cc * 2) ^ ((r & 7) << 4))) =
              f2bf(lrelu_f(acc[mt][nt][rg] + bm1v[nt]));
        }
  }
  __syncthreads();

  // ---- stage B (MFMA): h2 = lrelu(h1@Wm2^T+bm2)
#pragma unroll
  for (int a = 0; a < 2; a++)
#pragma unroll
    for (int b = 0; b < 4; b++) acc[a][b] = (f32x4){0.f, 0.f, 0.f, 0.f};
#pragma unroll
  for (int kk = 0; kk < 8; kk++) {
    int kbyte = kk * 64 + lg * 16;
    bf16x8 bfr[4];
#pragma unroll
    for (int nt = 0; nt < 4; nt++) {
      int n = nc0 + nt * 16 + lr;
      bfr[nt] = *(const bf16x8*)((const char*)Wm2b + n * 512 + kbyte);
    }
#pragma unroll
    for (int mt = 0; mt < 2; mt++) {
      int r = mt * 16 + lr;
      bf16x8 af = *(bf16x8*)((char*)hb + r * 512 + (kbyte ^ ((r & 7) << 4)));
#pragma unroll
      for (int nt = 0; nt < 4; nt++)
        acc[mt][nt] = __builtin_amdgcn_mfma_f32_16x16x32_bf16(af, bfr[nt], acc[mt][nt], 0, 0, 0);
    }
  }
  __syncthreads();   // all reads of h1 complete before overwrite
  {
    float bm2v[4];
#pragma unroll
    for (int nt = 0; nt < 4; nt++) bm2v[nt] = bm2[nc0 + nt * 16 + lr];
#pragma unroll
    for (int mt = 0; mt < 2; mt++)
#pragma unroll
      for (int nt = 0; nt < 4; nt++)
#pragma unroll
        for (int rg = 0; rg < 4; rg++) {
          int r = mt * 16 + lg * 4 + rg;
          int cc = nc0 + nt * 16 + lr;
          *(unsigned short*)((char*)hb + r * 512 + ((cc * 2) ^ ((r & 7) << 4))) =
              f2bf(lrelu_f(acc[mt][nt][rg] + bm2v[nt]));
        }
  }
  __syncthreads();

  // ---- stage C: hf = h2@Wm3^T + x@Wsk^T  (x from LDS xsh)
  f32x4 acc2[2][4];
#pragma unroll
  for (int a = 0; a < 2; a++)
#pragma unroll
    for (int b = 0; b < 4; b++) acc2[a][b] = (f32x4){0.f, 0.f, 0.f, 0.f};
#pragma unroll
  for (int kk = 0; kk < 8; kk++) {
    int kbyte = kk * 64 + lg * 16;
    bf16x8 b3[4], bs[4];
#pragma unroll
    for (int nt = 0; nt < 4; nt++) {
      int n = nc0 + nt * 16 + lr;
      b3[nt] = *(const bf16x8*)((const char*)Wm3b + n * 512 + kbyte);
      bs[nt] = *(const bf16x8*)((const char*)Wskb + n * 512 + kbyte);
    }
#pragma unroll
    for (int mt = 0; mt < 2; mt++) {
      int r = mt * 16 + lr;
      bf16x8 a2 = *(bf16x8*)((char*)hb + r * 512 + (kbyte ^ ((r & 7) << 4)));
      bf16x8 xv = *(bf16x8*)((char*)xsh + r * 512 + (kbyte ^ ((r & 7) << 4)));
#pragma unroll
      for (int nt = 0; nt < 4; nt++)
        acc2[mt][nt] = __builtin_amdgcn_mfma_f32_16x16x32_bf16(a2, b3[nt], acc2[mt][nt], 0, 0, 0);
#pragma unroll
      for (int nt = 0; nt < 4; nt++)
        acc2[mt][nt] = __builtin_amdgcn_mfma_f32_16x16x32_bf16(xv, bs[nt], acc2[mt][nt], 0, 0, 0);
    }
  }
#pragma unroll
  for (int nt = 0; nt < 4; nt++) {
    int cc = nc0 + nt * 16 + lr;
    float bb = bm3[cc] + bsk[cc];
#pragma unroll
    for (int mt = 0; mt < 2; mt++)
#pragma unroll
      for (int rg = 0; rg < 4; rg++) acc2[mt][nt][rg] += bb;
  }

  // ---- LayerNorm stats in registers
#pragma unroll
  for (int mt = 0; mt < 2; mt++)
#pragma unroll
    for (int rg = 0; rg < 4; rg++) {
      float s = 0.f, q = 0.f;
#pragma unroll
      for (int nt = 0; nt < 4; nt++) {
        float v = acc2[mt][nt][rg];
        s += v; q += v * v;
      }
#pragma unroll
      for (int m = 1; m < 16; m <<= 1) {
        s += __shfl_xor(s, m);
        q += __shfl_xor(q, m);
      }
      if (lr == 0) {
        int r = mt * 16 + lg * 4 + rg;
        redS[wv * 32 + r] = s;
        redQ[wv * 32 + r] = q;
      }
    }
  __syncthreads();
  if (tid < 32) {
    float s = 0.f, q = 0.f;
#pragma unroll
    for (int w = 0; w < 4; w++) { s += redS[w * 32 + tid]; q += redQ[w * 32 + tid]; }
    float m = s * (1.f / 256.f);
    float var = q * (1.f / 256.f) - m * m;
    mrow[tid] = m;
    irow[tid] = rsqrtf(var + 1e-5f);
  }
  __syncthreads();

  // ---- normalize + store (f32 coalesced only)
  {
    float lnwv[4], lnbv[4];
#pragma unroll
    for (int nt = 0; nt < 4; nt++) {
      int cc = nc0 + nt * 16 + lr;
      lnwv[nt] = lnw[cc]; lnbv[nt] = lnb[cc];
    }
#pragma unroll
    for (int mt = 0; mt < 2; mt++)
#pragma unroll
      for (int rg = 0; rg < 4; rg++) {
        int r = mt * 16 + lg * 4 + rg;
        float m = mrow[r], is = irow[r];
        size_t gr = (rbase + r) * DD;
#pragma unroll
        for (int nt = 0; nt < 4; nt++) {
          int cc = nc0 + nt * 16 + lr;
          float y = (acc2[mt][nt][rg] - m) * is * lnwv[nt] + lnbv[nt];
          if (WY) yout[gr + cc] = y;
          if (WX) xnext[gr + cc] = xsrc[gr + cc] + y;
        }
      }
  }
}

// ---------------------------------------------------------------------------
extern "C" void kernel_launch(void* const* d_in, const int* in_sizes, int n_in,
                              void* d_out, int out_size, void* d_ws, size_t ws_size,
                              hipStream_t stream) {
  const float* x_in = (const float*)d_in[0];
  const void*  startp = d_in[1];
  const float* s0  = (const float*)d_in[2];
  const float* z0  = (const float*)d_in[3];
  const float* Wk  = (const float*)d_in[4];
  const float* Wq  = (const float*)d_in[5];
  const float* Wv  = (const float*)d_in[6];
  const float* bv  = (const float*)d_in[7];
  const float* Wsk = (const float*)d_in[8];
  const float* bsk = (const float*)d_in[9];
  const float* Wm1 = (const float*)d_in[10];
  const float* bm1 = (const float*)d_in[11];
  const float* Wm2 = (const float*)d_in[12];
  const float* bm2 = (const float*)d_in[13];
  const float* Wm3 = (const float*)d_in[14];
  const float* bm3 = (const float*)d_in[15];
  const float* lnw = (const float*)d_in[16];
  const float* lnb = (const float*)d_in[17];
  float* yout = (float*)d_out;

  float* ws = (float*)d_ws;
  int*   flags   = (int*)d_ws;
  float* start_f = ws + 16;
  float* kbuf    = start_f + TT;
  float* qbuf    = kbuf + (size_t)TT * KV;
  float* vbuf    = qbuf + (size_t)TT * KV;
  float* abuf    = vbuf + (size_t)TT * KV;
  float* ts      = abuf + (size_t)TT * KV;
  float* tz      = ts + (size_t)NCH * 256;
  float* tf      = tz + NCH;
  float* xcur    = tf + NCH;                                // T*D f32
  unsigned short* wm2b = (unsigned short*)(xcur + (size_t)TT * DD);
  unsigned short* wm3b = wm2b + (size_t)NBLK * HH * HH;
  unsigned short* wskb = wm3b + (size_t)NBLK * HH * HH;
  unsigned short* wpjh = wskb + (size_t)NBLK * HH * DD;     // [b][48][256] hi
  unsigned short* wpjl = wpjh + (size_t)NBLK * 48 * DD;     // [b][48][256] lo
  unsigned short* wm1h = wpjl + (size_t)NBLK * 48 * DD;     // [b][256][32]
  unsigned short* wm1l = wm1h + (size_t)NBLK * HH * 32;

  hipMemsetAsync(d_ws, 0, 64, stream);
  k_detect<<<64, 256, 0, stream>>>(startp, flags);
  k_canon<<<256, 256, 0, stream>>>(startp, flags, start_f);

  k_cvtbig<<<192, 256, 0, stream>>>(Wm2, Wm3, Wsk, wm2b, wm3b, wskb, NBLK * HH * HH);
  k_cvtproj<<<12, 256, 0, stream>>>(Wk, Wq, Wv, wpjh, wpjl);
  k_cvtm1<<<2, 256, 0, stream>>>(Wm1, wm1h, wm1l);

  const float* xs = x_in;
  for (int b = 0; b < NBLK; b++) {
    k_projt<<<TT / 64, 256, 0, stream>>>(xs,
        wpjh + (size_t)b * 48 * DD, wpjl + (size_t)b * 48 * DD,
        bv + (size_t)b * KV, start_f, kbuf, qbuf, vbuf, ts, tz, tf);
    k_att<<<NCH, 256, 0, stream>>>(qbuf, kbuf, vbuf, start_f, ts, tz, tf,
        s0 + (size_t)b * 256, z0 + (size_t)b * KV, abuf);
    if (b == 0) {
      k_mlp6<0, 1><<<TT / 32, 256, 0, stream>>>(abuf, xs,
          wm1h + (size_t)b * HH * 32, wm1l + (size_t)b * HH * 32, bm1 + (size_t)b * HH,
          wm2b + (size_t)b * HH * HH, bm2 + (size_t)b * HH,
          wm3b + (size_t)b * HH * HH, bm3 + (size_t)b * HH,
          wskb + (size_t)b * HH * DD, bsk + (size_t)b * HH,
          lnw + (size_t)b * HH, lnb + (size_t)b * HH, yout, xcur);
    } else {
      k_mlp6<1, 0><<<TT / 32, 256, 0, stream>>>(abuf, xs,
          wm1h + (size_t)b * HH * 32, wm1l + (size_t)b * HH * 32, bm1 + (size_t)b * HH,
          wm2b + (size_t)b * HH * HH, bm2 + (size_t)b * HH,
          wm3b + (size_t)b * HH * HH, bm3 + (size_t)b * HH,
          wskb + (size_t)b * HH * DD, bsk + (size_t)b * HH,
          lnw + (size_t)b * HH, lnb + (size_t)b * HH, yout, xcur);
    }
    xs = xcur;
  }
}